// Round 1
// baseline (330.640 us; speedup 1.0000x reference)
//
#include <hip/hip_runtime.h>

typedef float  f32x4  __attribute__((ext_vector_type(4)));
typedef __bf16 bf16x8 __attribute__((ext_vector_type(8)));
typedef unsigned short u16x8 __attribute__((ext_vector_type(8)));

// round-to-nearest-even float -> bf16 bits
static __device__ __forceinline__ unsigned short f2bf(float f) {
  union { float f; unsigned int u; } a; a.f = f;
  unsigned int r = (a.u + 0x7FFFu + ((a.u >> 16) & 1u)) >> 16;
  return (unsigned short)r;
}

// Pre-fragize weights into d_ws: bf16, MFMA-B fragment order.
// Element index: ((w*32 + n*4 + kk)*512) + p*8 + i
// holds W_w[kk*32 + (p>>4)*8 + i][n*16 + (p&15)]
__global__ void prep_weights(const float* __restrict__ Wq, const float* __restrict__ Wk,
                             const float* __restrict__ Wv, unsigned short* __restrict__ wf) {
  int idx = blockIdx.x * 256 + threadIdx.x;
  if (idx >= 3 * 8 * 4 * 64 * 8) return;
  int i  = idx & 7;
  int p  = (idx >> 3) & 63;
  int kk = (idx >> 9) & 3;
  int n  = (idx >> 11) & 7;
  int w  = idx >> 14;
  const float* W = (w == 0) ? Wq : ((w == 1) ? Wk : Wv);
  int k   = kk * 32 + (p >> 4) * 8 + i;
  int col = n * 16 + (p & 15);
  wf[idx] = f2bf(W[k * 128 + col]);
}

__global__ __launch_bounds__(256, 2) void attn_main(
    const float* __restrict__ xin, const float* __restrict__ pos,
    const unsigned short* __restrict__ wfrag, float* __restrict__ out, int B) {
  // per-wave private: [wave][stage: 0=Q,1=K,2=V,3=attn][local head][512 bf16 = 1KB frag region]
  __shared__ __align__(16) unsigned short lds[4][4][2][512];
  const int tid = threadIdx.x;
  const int wid = tid >> 6;
  const int l   = tid & 63;
  const int n0  = wid * 2;           // first global head owned by this wave
  const int frow = l & 15;           // fragment row / D-col index
  const int fkq  = l >> 4;           // fragment k-quadrant
  const int trow0 = fkq * 4;         // first acc row this lane owns (D layout)

  // zero own wave's 8KB LDS slice (upper frag halves must be 0 for K=16->32 padding)
  {
    u16x8* zp = (u16x8*)&lds[wid][0][0][0];
    u16x8 z = {0, 0, 0, 0, 0, 0, 0, 0};
#pragma unroll
    for (int j = 0; j < 8; ++j) zp[j * 64 + l] = z;
  }

  // weight B-fragments for this wave's 2 heads: 3 W x 2 heads x 4 K-steps, 96 VGPRs
  bf16x8 wf[3][2][4];
#pragma unroll
  for (int w = 0; w < 3; ++w)
#pragma unroll
    for (int hl = 0; hl < 2; ++hl)
#pragma unroll
      for (int kk = 0; kk < 4; ++kk) {
        int off = ((w * 32 + (n0 + hl) * 4 + kk) * 512) + l * 8;
        wf[w][hl][kk] = __builtin_bit_cast(bf16x8, *(const u16x8*)(wfrag + off));
      }

  // pos_emb in A-fragment layout (batch-invariant)
  f32x4 posf[4][2];
#pragma unroll
  for (int kk = 0; kk < 4; ++kk) {
    const float* pp = pos + frow * 128 + kk * 32 + fkq * 8;
    posf[kk][0] = *(const f32x4*)pp;
    posf[kk][1] = *(const f32x4*)(pp + 4);
  }
  // pos_emb for pass-through rows 4*wid..4*wid+3
  f32x4 posp[2];
#pragma unroll
  for (int j = 0; j < 2; ++j)
    posp[j] = *(const f32x4*)(pos + wid * 512 + j * 256 + l * 4);

  const float sc    = 0.24253562503633297f;  // 1/sqrt(17)
  const float LOG2E = 1.4426950408889634f;

  for (int b = blockIdx.x; b < B; b += gridDim.x) {
    const float* xb = xin + (size_t)b * 2048;
    float* ob = out + (size_t)b * 4096;

    // ---- pass-through: out[:, :, 128:256] = x + pos (fp32 exact) ----
#pragma unroll
    for (int j = 0; j < 2; ++j) {
      int f = wid * 512 + j * 256 + l * 4;
      f32x4 v = *(const f32x4*)(xb + f);
      v += posp[j];
      *(f32x4*)(ob + (f >> 7) * 256 + 128 + (f & 127)) = v;
    }

    // ---- x A-fragments (add pos, cvt bf16) ----
    bf16x8 xf[4];
#pragma unroll
    for (int kk = 0; kk < 4; ++kk) {
      const float* xp = xb + frow * 128 + kk * 32 + fkq * 8;
      f32x4 a0 = *(const f32x4*)xp + posf[kk][0];
      f32x4 a1 = *(const f32x4*)(xp + 4) + posf[kk][1];
      union { unsigned short us[8]; bf16x8 v; } u;
      u.us[0] = f2bf(a0.x); u.us[1] = f2bf(a0.y); u.us[2] = f2bf(a0.z); u.us[3] = f2bf(a0.w);
      u.us[4] = f2bf(a1.x); u.us[5] = f2bf(a1.y); u.us[6] = f2bf(a1.z); u.us[7] = f2bf(a1.w);
      xf[kk] = u.v;
    }

    // ---- QKV projections for this wave's 2 heads; stage to LDS in frag order ----
    const int c = frow;  // D-layout col (tile-local feature / key index)
#pragma unroll
    for (int w = 0; w < 3; ++w) {
#pragma unroll
      for (int hl = 0; hl < 2; ++hl) {
        f32x4 acc = {0.f, 0.f, 0.f, 0.f};
#pragma unroll
        for (int kk = 0; kk < 4; ++kk)
          acc = __builtin_amdgcn_mfma_f32_16x16x32_bf16(xf[kk], wf[w][hl][kk], acc, 0, 0, 0);
#pragma unroll
        for (int r = 0; r < 4; ++r) {
          int row = trow0 + r;
          int lpos, ii;
          if (w < 2) { lpos = row | ((c >> 3) << 4); ii = c & 7; }   // Q,K: A/B frag over k=dh
          else       { lpos = c | ((row >> 3) << 4); ii = row & 7; } // V: B frag over k=s
          lds[wid][w][hl][lpos * 8 + ii] = f2bf(acc[r]);
        }
      }
    }
    asm volatile("s_waitcnt lgkmcnt(0)" ::: "memory");

    // ---- scores + softmax + attn staging ----
#pragma unroll
    for (int hl = 0; hl < 2; ++hl) {
      bf16x8 qa = __builtin_bit_cast(bf16x8, *(const u16x8*)&lds[wid][0][hl][l * 8]);
      bf16x8 kb = __builtin_bit_cast(bf16x8, *(const u16x8*)&lds[wid][1][hl][l * 8]);
      f32x4 sacc = {0.f, 0.f, 0.f, 0.f};
      sacc = __builtin_amdgcn_mfma_f32_16x16x32_bf16(qa, kb, sacc, 0, 0, 0);
#pragma unroll
      for (int r = 0; r < 4; ++r) {
        int t = trow0 + r;           // query time
        float sv = sacc[r] * sc;     // key time = c
        if (c > t) sv = -1e30f;      // causal mask
        float m = sv;
#pragma unroll
        for (int mk = 8; mk; mk >>= 1) m = fmaxf(m, __shfl_xor(m, mk));
        float p = exp2f((sv - m) * LOG2E);
        float ssum = p;
#pragma unroll
        for (int mk = 8; mk; mk >>= 1) ssum += __shfl_xor(ssum, mk);
        float a = p / ssum;
        int lpos = t | ((c >> 3) << 4);
        lds[wid][3][hl][lpos * 8 + (c & 7)] = f2bf(a);
      }
    }
    asm volatile("s_waitcnt lgkmcnt(0)" ::: "memory");

    // ---- PV + epilogue (relu(o)+o), scatter-store o columns ----
#pragma unroll
    for (int hl = 0; hl < 2; ++hl) {
      bf16x8 pa = __builtin_bit_cast(bf16x8, *(const u16x8*)&lds[wid][3][hl][l * 8]);
      bf16x8 vb = __builtin_bit_cast(bf16x8, *(const u16x8*)&lds[wid][2][hl][l * 8]);
      f32x4 oacc = {0.f, 0.f, 0.f, 0.f};
      oacc = __builtin_amdgcn_mfma_f32_16x16x32_bf16(pa, vb, oacc, 0, 0, 0);
#pragma unroll
      for (int r = 0; r < 4; ++r) {
        int t = trow0 + r;
        float ov = oacc[r];
        ov = ov > 0.f ? 2.f * ov : ov;
        ob[t * 256 + (n0 + hl) * 16 + c] = ov;
      }
    }
  }
}

extern "C" void kernel_launch(void* const* d_in, const int* in_sizes, int n_in,
                              void* d_out, int out_size, void* d_ws, size_t ws_size,
                              hipStream_t stream) {
  (void)n_in; (void)out_size; (void)ws_size;
  const float* xin = (const float*)d_in[0];
  const float* pos = (const float*)d_in[1];
  const float* Wq  = (const float*)d_in[2];
  const float* Wk  = (const float*)d_in[3];
  const float* Wv  = (const float*)d_in[4];
  float* out = (float*)d_out;
  unsigned short* wf = (unsigned short*)d_ws;  // 96 KiB used
  int B = in_sizes[0] / 2048;

  hipLaunchKernelGGL(prep_weights, dim3(192), dim3(256), 0, stream, Wq, Wk, Wv, wf);
  hipLaunchKernelGGL(attn_main, dim3(2048), dim3(256), 0, stream, xin, pos, wf, out, B);
}